// Round 6
// baseline (308.700 us; speedup 1.0000x reference)
//
#include <hip/hip_runtime.h>
#include <math.h>

#define NB 16
#define HH 512
#define WW 512
#define HW (HH * WW)
#define CHW (8 * HW)
#define NSEG 8   // 64-px tiles per 512-px row-pair

typedef const __attribute__((address_space(1))) void* gvp;
typedef __attribute__((address_space(3))) void*       lvp;

// t is exactly 0.0/1.0: BCE elem = -max(log(t ? p : 1-p), -100)
__device__ __forceinline__ float bce_term(float t, float p) {
    float q = (t > 0.5f) ? p : (1.0f - p);
    return -fmaxf(__logf(q), -100.0f);
}

// Wave-private DMA pipeline, ALL inputs staged via global_load_lds (no VGPR
// destination loads in the loop -> nothing forces the prefetch to drain).
// R5 bug fixed: the one scalar (edge) load is issued BEFORE the t+1 DMAs, so
// its consumption needs only vmcnt(11) and never drains the prefetch (vmcnt
// retires strictly in issue order).
// Loss math in log-of-product form: 12 logs/iter instead of 34.
__global__ __launch_bounds__(128, 2) void bicon_loss_kernel(
    const float* __restrict__ c_map,
    const float* __restrict__ target,
    const float* __restrict__ con_target,
    float* __restrict__ out)
{
    // per wave: [2 bufs][40 planes][64 cols] = 20 KB -> 40 KB/block, 4 blocks/CU
    // planes 0-2: c_map row h0-1 ch{5,6,7}; 3-10: row h0 ch0-7; 11-18: row h0+1
    // ch0-7; 19-21: row h0+2 ch{0,1,2}; 22-23: target rows h0,h0+1;
    // 24-31: con_target row h0 ch0-7; 32-39: con_target row h0+1 ch0-7.
    __shared__ float buf[2][2][40][64];

    const int tid  = threadIdx.x;
    const int wave = tid >> 6;
    const int lane = tid & 63;
    const int wid  = blockIdx.x * 2 + wave;   // 4096 waves
    const int b    = wid >> 8;
    const int h0   = (wid & 255) << 1;

    // ---- DMA lane pointers: instr s covers planes 4s..4s+3; lane's plane =
    // 4s + (lane>>4), column slice (lane&15)*16B.
    const float* dma_ptr[10];
    #pragma unroll
    for (int s = 0; s < 10; ++s) {
        const int pp = s * 4 + (lane >> 4);
        const float* base;
        if (pp < 22) {
            int ch, rel;
            if (pp < 3)       { ch = 5 + pp;  rel = -1; }
            else if (pp < 11) { ch = pp - 3;  rel = 0;  }
            else if (pp < 19) { ch = pp - 11; rel = 1;  }
            else              { ch = pp - 19; rel = 2;  }
            int rr = h0 + rel; rr = rr < 0 ? 0 : (rr > HH - 1 ? HH - 1 : rr);
            base = c_map + b * CHW + ch * HW + rr * WW;
        } else if (pp < 24) {
            base = target + b * HW + (h0 + pp - 22) * WW;
        } else if (pp < 32) {
            base = con_target + b * CHW + (pp - 24) * HW + h0 * WW;
        } else {
            base = con_target + b * CHW + (pp - 32) * HW + (h0 + 1) * WW;
        }
        dma_ptr[s] = base + (lane & 15) * 4;
    }

    // ---- edge pointer (R5-verified): lane k<12 loads edge value k.
    // k even -> col w0+64 (R), k odd -> col w0-1 (L); kk=k>>1:
    // chR={5,3,2,3,5,2}, chL={7,4,0,4,7,0}, rel+1={0,1,2,2,1,3}
    const int k     = lane < 12 ? lane : 0;
    const int kk4   = (k >> 1) * 4;
    const int dirR  = ((k & 1) == 0);
    const int ch_e  = dirR ? ((0x253235 >> kk4) & 15) : ((0x074047 >> kk4) & 15);
    const int rel_e = ((0x312210 >> kk4) & 15) - 1;
    int rre = h0 + rel_e; rre = rre < 0 ? 0 : (rre > HH - 1 ? HH - 1 : rre);
    const float* eptr = c_map + b * CHW + ch_e * HW + rre * WW + (dirR ? 64 : -1);

    float (*mybuf)[40][64] = buf[wave];

    // ---- prologue: edge scalar FIRST, fence, then tile-0 DMAs ----
    float ex_cur = eptr[0];
    asm volatile("" ::: "memory");
    #pragma unroll
    for (int s = 0; s < 10; ++s)
        __builtin_amdgcn_global_load_lds((gvp)dma_ptr[s], (lvp)&mybuf[0][s * 4][0], 16, 0, 0);

    const bool hu  = (h0 > 0);
    const bool hd2 = (h0 < HH - 2);

    float acc_con = 0.0f, acc_bi = 0.0f, acc_de = 0.0f;

    for (int t = 0; t < NSEG; ++t) {
        const int par = t & 1;
        float ex_next = 0.0f;
        if (t + 1 < NSEG) {
            const int w1 = (t + 1) << 6;
            ex_next = eptr[w1];                       // older than the DMAs below
            asm volatile("" ::: "memory");
            #pragma unroll
            for (int s = 0; s < 10; ++s)
                __builtin_amdgcn_global_load_lds((gvp)(dma_ptr[s] + w1),
                                                 (lvp)&mybuf[(t + 1) & 1][s * 4][0], 16, 0, 0);
            __builtin_amdgcn_s_waitcnt(0x0F7B);       // vmcnt(11): drain tile t, keep t+1
        } else {
            __builtin_amdgcn_s_waitcnt(0x0F70);       // vmcnt(0): last tile
        }
        asm volatile("" ::: "memory");                // no ds_read hoist above the wait

        const int gw = (t << 6) + lane;
        const bool wl = (gw > 0), wr = (gw < WW - 1);

        // ---- LDS reads ----
        float xv[22];
        #pragma unroll
        for (int pp = 0; pp < 22; ++pp) xv[pp] = mybuf[par][pp][lane];
        const float tg0 = mybuf[par][22][lane];
        const float tg1 = mybuf[par][23][lane];
        float tv0[8], tv1[8];
        #pragma unroll
        for (int c = 0; c < 8; ++c) {
            tv0[c] = mybuf[par][24 + c][lane];
            tv1[c] = mybuf[par][32 + c][lane];
        }

        float u[22];
        #pragma unroll
        for (int pp = 0; pp < 22; ++pp) u[pp] = 1.0f + __expf(-xv[pp]);
        const float ue = 1.0f + __expf(-ex_cur);

        #define U0(c) u[3 + (c)]
        #define U1(c) u[11 + (c)]
        auto SHP = [&](float v, int ek) -> float {   // u at col w+1
            float s = __shfl(v, (lane + 1) & 63, 64);
            float e = __shfl(ue, ek, 64);
            return (lane == 63) ? e : s;
        };
        auto SHM = [&](float v, int ek) -> float {   // u at col w-1
            float s = __shfl(v, (lane + 63) & 63, 64);
            float e = __shfl(ue, ek, 64);
            return (lane == 0) ? e : s;
        };

        // ---- neighbor u's (R5-verified wiring) ----
        const float m4   = SHM(U0(4), 3),  m3   = SHP(U0(3), 2);
        const float n5   = SHP(u[0], 0),   n6   = u[1],  n7 = SHM(u[2], 1);
        const float dn1  = U1(1), dn2 = SHP(U1(2), 4), dn0 = SHM(U1(0), 5);
        const float m4b  = SHM(U1(4), 7),  m3b  = SHP(U1(3), 6);
        const float n5b  = SHP(U0(5), 8),  n6b  = U0(6), n7b = SHM(U0(7), 9);
        const float dn1b = u[20], dn2b = SHP(u[21], 10), dn0b = SHM(u[19], 11);

        // votes in stack order [a7,a3,a5,a1,a2,a6,a4,a8]; w = u_c*u_n (v=1/w)
        float wv0[8], wv1[8];
        bool  va0[8], va1[8];
        wv0[0] = U0(0) * n7;   va0[0] = hu && wl;
        wv0[1] = U0(1) * n6;   va0[1] = hu;
        wv0[2] = U0(2) * n5;   va0[2] = hu && wr;
        wv0[3] = U0(3) * m4;   va0[3] = wl;
        wv0[4] = U0(4) * m3;   va0[4] = wr;
        wv0[5] = U0(5) * dn2;  va0[5] = wr;
        wv0[6] = U0(6) * dn1;  va0[6] = true;
        wv0[7] = U0(7) * dn0;  va0[7] = wl;
        wv1[0] = U1(0) * n7b;  va1[0] = wl;
        wv1[1] = U1(1) * n6b;  va1[1] = true;
        wv1[2] = U1(2) * n5b;  va1[2] = wr;
        wv1[3] = U1(3) * m4b;  va1[3] = wl;
        wv1[4] = U1(4) * m3b;  va1[4] = wr;
        wv1[5] = U1(5) * dn2b; va1[5] = hd2 && wr;
        wv1[6] = U1(6) * dn1b; va1[6] = hd2;
        wv1[7] = U1(7) * dn0b; va1[7] = hd2 && wl;

        // ---- conmap: sum log u = log(prod u); + (1-t)*x linear terms ----
        float P0 = 1.0f, P1 = 1.0f, lin = 0.0f;
        #pragma unroll
        for (int c = 0; c < 8; ++c) {
            P0 *= u[3 + c];   lin += (tv0[c] > 0.5f) ? 0.0f : xv[3 + c];
            P1 *= u[11 + c];  lin += (tv1[c] > 0.5f) ? 0.0f : xv[11 + c];
        }
        acc_con += __logf(P0) + __logf(P1) + lin;

        // ---- bimap (quad products) + de, per row ----
        auto row_loss = [&](const float* wv, const bool* va, const float* tv,
                            float tg) {
            float pW0 = 1.0f, pW1 = 1.0f, pQ0 = 1.0f, pQ1 = 1.0f;
            float corr = 0.0f, sumc = 0.0f, sumv = 0.0f, vmin = 1.0f;
            #pragma unroll
            for (int c = 0; c < 8; ++c) {
                const float tt = tv[c];
                const float w  = wv[c];
                const bool  va_c = va[c];
                sumc += tt;
                const float wp = va_c ? w : 1.0f;
                const float qq = (va_c && tt < 0.5f) ? (w - 1.0f) : 1.0f;
                corr += (!va_c && tt > 0.5f) ? 100.0f : 0.0f;
                if (c < 4) { pW0 *= wp; pQ0 *= qq; }
                else       { pW1 *= wp; pQ1 *= qq; }
                const float vv = va_c ? __fdividef(1.0f, w) : 0.0f;
                sumv += vv;
                vmin = fminf(vmin, vv);
            }
            acc_bi += __logf(pW0) + __logf(pW1) - __logf(pQ0) - __logf(pQ1) + corr;
            const bool edge = (sumc < 8.0f) && (sumc > 0.0f);
            const float dec = edge ? (1.0f - vmin) : (0.125f * sumv);
            acc_de += bce_term(tg, dec);
        };
        row_loss(wv0, va0, tv0, tg0);
        row_loss(wv1, va1, tv1, tg1);

        ex_cur = ex_next;
        #undef U0
        #undef U1
    }

    // ---- reduction: wave shuffle -> one atomic per wave (no barrier) ----
    float local = fmaf(0.8f, acc_con, fmaf(0.2f, acc_bi, acc_de));
    #pragma unroll
    for (int off = 32; off > 0; off >>= 1)
        local += __shfl_down(local, off, 64);
    if (lane == 0) atomicAdd(out, local);
}

extern "C" void kernel_launch(void* const* d_in, const int* in_sizes, int n_in,
                              void* d_out, int out_size, void* d_ws, size_t ws_size,
                              hipStream_t stream) {
    const float* c_map      = (const float*)d_in[0];
    const float* target     = (const float*)d_in[1];
    const float* con_target = (const float*)d_in[2];
    float* out = (float*)d_out;

    hipMemsetAsync(out, 0, sizeof(float), stream);

    const int blocks = (NB * (HH / 2)) / 2;   // 4096 waves / 2 per block = 2048
    bicon_loss_kernel<<<blocks, 128, 0, stream>>>(c_map, target, con_target, out);
}